// Round 2
// baseline (226.032 us; speedup 1.0000x reference)
//
#include <hip/hip_runtime.h>

// ForwardKinematics: B=65536 bodies, N=24 joints, compile-time parent tree.
//
// Round 5 = round 4 with the compile fix: __builtin_nontemporal_store needs
// a NATIVE vector type (ext_vector_type), not HIP's float4 class.
//
// Round 4: 4 lanes per body (row-split). The three rows of the chained
// transform Rg[i] = Rg[parent] * R_i are independent serial chains: row r of
// Rg[i] needs only row r of Rg[parent] plus the full (read-only) local R_i.
// Lanes r=0,1,2 of each quad own one row-chain each; lane r=3 owns the
// constant bottom row (0,0,0,1).
//
// Why: the one-thread-per-body kernel had 65536 threads = 1024 waves =
// exactly 1 wave/SIMD (grid-limited occupancy) and ~500 VGPRs of state;
// every memory wait was exposed, landing at ~4.5 TB/s vs the ~6.3 TB/s
// mixed ceiling. Row-splitting gives 4096 waves (4/SIMD), shrinks per-lane
// state to a ~5-joint liveness window (<128 VGPR so all 4 waves fit), and
// makes rel stores direct-from-register: each quad writes one full 64 B
// line per joint (16 full lines per store instruction) -- no LDS staging,
// no flush barriers for the 100 MB rel stream.
//
// Loads are per-joint and quad-uniform (same address in all 4 lanes of a
// quad -> coalescer broadcast; the 36 B/joint chunks are fully consumed by
// neighboring i-steps through L1/L2, so HBM still fetches each byte once).
// Only posed (18.9 MB) stages through a small LDS transpose so its writes
// are full-line too. Stores use the nt hint so the write stream doesn't
// evict the read stream from L2.

typedef float f32x4 __attribute__((ext_vector_type(4)));

constexpr int PARENTS[24] = {-1, 0, 0, 0, 1, 2, 3, 4, 5, 6, 7, 8,
                             9, 9, 9, 12, 13, 14, 16, 17, 18, 19, 20, 21};

// Wave-synchronous "barrier": one wave's DS ops execute in order in the DS
// pipe, so cross-lane LDS exchange inside a wave needs only a compiler
// code-motion fence, not s_barrier (carried over from round 3).
__device__ __forceinline__ void wave_sync() {
    asm volatile("" ::: "memory");
    __builtin_amdgcn_wave_barrier();
    asm volatile("" ::: "memory");
}

__global__ __launch_bounds__(256, 4)
void fk_kernel(const float* __restrict__ rot,   // (B,24,3,3)
               const float* __restrict__ jts,   // (B,24,3)
               float* __restrict__ posed,       // (B,24,3)
               float* __restrict__ rel,         // (B,24,4,4)
               int B)
{
    // posed staging: 64 bodies x 76 floats (stride 76 = 19 float4).
    // ds_write banks: (76*q + 3i + r) % 32 -> worst 2-way (free).
    // Flush reads b128 at stride 19 f4: worst ~2-way.
    __shared__ float smem[64 * 76];             // 19456 B

    const int tid  = threadIdx.x;
    const int w    = tid >> 6;                  // wave 0..3
    const int l    = tid & 63;                  // lane in wave
    const int q    = l >> 2;                    // body-in-wave 0..15
    const int r    = l & 3;                     // row lane (3 = bottom row)
    const int bw   = (w << 4) + q;              // body-in-block 0..63
    const int body = blockIdx.x * 64 + bw;
    const bool rowlane = (r < 3);

    const float* Rb = rot + (size_t)body * 216;
    const float* Jb = jts + (size_t)body * 72;
    f32x4* relG = reinterpret_cast<f32x4*>(rel) + (size_t)body * 96;

    // Per-joint saved state. Constant-indexed after full unroll -> promoted
    // to registers with true liveness (a joint's row/translation/position
    // die after its last child is processed; max ~5 pending joints).
    float jx[24], jy[24], jz[24];
    float a0[24], a1[24], a2[24];   // this lane's row of the global rotation
    float tg[24];                   // this lane's component of global translation

#pragma unroll
    for (int i = 0; i < 24; ++i) {
        // Quad-uniform joint load (12 B, broadcast across the quad's lanes).
        const float jix = Jb[3*i+0], jiy = Jb[3*i+1], jiz = Jb[3*i+2];
        jx[i] = jix; jy[i] = jiy; jz[i] = jiz;

        float b0, b1, b2, t;
        if (i == 0) {
            // Root: own row of R_0 (runtime-r address), t = j0[r].
            // Lane r=3 reads joint 1's data -- in-bounds garbage, masked at
            // the store below.
            b0 = Rb[3*r+0]; b1 = Rb[3*r+1]; b2 = Rb[3*r+2];
            t  = Jb[r];
        } else {
            // Full local R_i (9 floats, quad-uniform).
            const float* ri = Rb + 9*i;
            const float R00=ri[0], R01=ri[1], R02=ri[2];
            const float R10=ri[3], R11=ri[4], R12=ri[5];
            const float R20=ri[6], R21=ri[7], R22=ri[8];
            const int p = PARENTS[i];
            const float c0 = a0[p], c1 = a1[p], c2 = a2[p];
            const float rl0 = jix - jx[p], rl1 = jiy - jy[p], rl2 = jiz - jz[p];
            b0 = c0*R00 + c1*R10 + c2*R20;
            b1 = c0*R01 + c1*R11 + c2*R21;
            b2 = c0*R02 + c1*R12 + c2*R22;
            t  = c0*rl0 + c1*rl1 + c2*rl2 + tg[p];
        }
        a0[i] = b0; a1[i] = b1; a2[i] = b2; tg[i] = t;

        // rel row: [row | t - row.j_i]; lane 3 substitutes (0,0,0,1).
        const float tc = t - (b0*jix + b1*jiy + b2*jiz);
        f32x4 out;
        if (rowlane) { out.x = b0; out.y = b1; out.z = b2; out.w = tc; }
        else         { out.x = 0.f; out.y = 0.f; out.z = 0.f; out.w = 1.f; }
        // Quad writes 64 B contiguous; 16 full cache lines per instruction.
        __builtin_nontemporal_store(out, relG + 4*i + r);

        // Stage this lane's posed component (masked: lane 3 would collide).
        if (rowlane) smem[bw*76 + 3*i + r] = t;
    }

    wave_sync();   // order own-wave ds_writes before the transpose reads

    // posed flush: this wave's 16 bodies are contiguous -> 288 float4.
    const f32x4* s4 = reinterpret_cast<const f32x4*>(smem) + w * 304; // 16*19
    f32x4* pos4 = reinterpret_cast<f32x4*>(posed)
                + ((size_t)blockIdx.x * 64 + (w << 4)) * 18;
#pragma unroll
    for (int t5 = 0; t5 < 5; ++t5) {
        const int g = t5*64 + l;                // 0..319, need < 288
        if (g < 288) {
            const int bdy = g / 18;             // magic-mul division
            const int k   = g - bdy*18;
            const f32x4 v = s4[bdy*19 + k];
            __builtin_nontemporal_store(v, pos4 + g);
        }
    }
}

extern "C" void kernel_launch(void* const* d_in, const int* in_sizes, int n_in,
                              void* d_out, int out_size, void* d_ws, size_t ws_size,
                              hipStream_t stream) {
    const float* rot = (const float*)d_in[0];   // (B,24,3,3)
    const float* jts = (const float*)d_in[1];   // (B,24,3)
    const int B = in_sizes[1] / 72;             // 24*3 floats per body

    float* posed = (float*)d_out;                       // B*24*3
    float* rel   = posed + (size_t)B * 72;              // B*24*16

    const int block = 256;                      // 4 waves, 64 bodies/block
    const int grid  = B / 64;                   // 65536 -> 1024 blocks
    hipLaunchKernelGGL(fk_kernel, dim3(grid), dim3(block), 0, stream,
                       rot, jts, posed, rel, B);
}

// Round 3
// 211.275 us; speedup vs baseline: 1.0698x; 1.0698x over previous
//
#include <hip/hip_runtime.h>

// ForwardKinematics: B=65536 bodies, N=24 joints, compile-time parent tree.
//
// Round 6: row-split (round 5) + explicit rolling prefetch.
//
// Round-5 post-mortem: VGPR=36, VALUBusy=4.6%, 1.8 TB/s, 100 us -- the
// compiler scheduled each joint's R/J loads just-in-time inside the unrolled
// chain (register-pressure-minimizing schedule), so MLP ~= 1 joint (~96 B
// per lane in flight). Little's law at ~600 cy HBM/L3 latency gives exactly
// the observed 1.8 TB/s. The loads are chain-INDEPENDENT; only the schedule
// serialized them.
//
// Fix: rolling prefetch window of PF=4 joints (pR/pJ arrays, constant-indexed
// after full unroll -> registers). Joint i+4's loads issue before joint i's
// FMAs; in-flight bytes/lane rise to ~192 B x 4 waves/SIMD -> BW-bound, not
// latency-bound. 48 prefetch VGPRs + ~60 state keeps total under 128 so the
// grid-provided 4 waves/SIMD still fit.
//
// Carried from round 5: 4 lanes/body row-split (lanes 0-2 own one row-chain
// each, lane 3 the constant bottom row); rel stores direct-from-register,
// one full 64 B line per quad per joint, nontemporal; posed staged through
// a 19 KB LDS transpose (now batched after the chain -- tg[] is already
// register-resident) and flushed as full lines.

typedef float f32x4 __attribute__((ext_vector_type(4)));

constexpr int PARENTS[24] = {-1, 0, 0, 0, 1, 2, 3, 4, 5, 6, 7, 8,
                             9, 9, 9, 12, 13, 14, 16, 17, 18, 19, 20, 21};
constexpr int PF = 4;   // prefetch distance (joints in flight per lane)

// Wave-synchronous "barrier": one wave's DS ops execute in order in the DS
// pipe; cross-lane LDS exchange inside a wave needs only a compiler fence.
__device__ __forceinline__ void wave_sync() {
    asm volatile("" ::: "memory");
    __builtin_amdgcn_wave_barrier();
    asm volatile("" ::: "memory");
}

__global__ __launch_bounds__(256, 4)
void fk_kernel(const float* __restrict__ rot,   // (B,24,3,3)
               const float* __restrict__ jts,   // (B,24,3)
               float* __restrict__ posed,       // (B,24,3)
               float* __restrict__ rel,         // (B,24,4,4)
               int B)
{
    // posed staging: 64 bodies x 76 floats (stride 76 = 19 float4).
    // ds_write banks (12bw+3i+r)%32: worst 2-way (free). Flush b128 reads
    // at stride 19 f4: worst ~2-way.
    __shared__ float smem[64 * 76];             // 19456 B

    const int tid  = threadIdx.x;
    const int w    = tid >> 6;                  // wave 0..3
    const int l    = tid & 63;                  // lane in wave
    const int q    = l >> 2;                    // body-in-wave 0..15
    const int r    = l & 3;                     // row lane (3 = bottom row)
    const int bw   = (w << 4) + q;              // body-in-block 0..63
    const int body = blockIdx.x * 64 + bw;
    const bool rowlane = (r < 3);

    const float* Rb = rot + (size_t)body * 216;
    const float* Jb = jts + (size_t)body * 72;
    f32x4* relG = reinterpret_cast<f32x4*>(rel) + (size_t)body * 96;

    // ---- Rolling prefetch buffers (constant-indexed -> registers).
    float pR[PF][9];
    float pJ[PF][3];
#pragma unroll
    for (int k = 0; k < PF; ++k) {
#pragma unroll
        for (int v = 0; v < 3; ++v) pJ[k][v] = Jb[3*k + v];
#pragma unroll
        for (int v = 0; v < 9; ++v) pR[k][v] = Rb[9*k + v];
    }
    // Root row for this lane (runtime r; lane 3 reads in-bounds garbage,
    // masked at the store).
    const float rb0 = Rb[3*r+0], rb1 = Rb[3*r+1], rb2 = Rb[3*r+2];
    const float rt  = Jb[r];

    // Per-joint saved state (constant-indexed after unroll -> registers
    // with true liveness; max ~5 pending joints live at once).
    float jx[24], jy[24], jz[24];
    float a0[24], a1[24], a2[24];   // this lane's row of the global rotation
    float tg[24];                   // this lane's component of global translation

#pragma unroll
    for (int i = 0; i < 24; ++i) {
        const int s = i % PF;       // constant-folded
        // Consume slot s.
        const float jix = pJ[s][0], jiy = pJ[s][1], jiz = pJ[s][2];
        const float R00 = pR[s][0], R01 = pR[s][1], R02 = pR[s][2];
        const float R10 = pR[s][3], R11 = pR[s][4], R12 = pR[s][5];
        const float R20 = pR[s][6], R21 = pR[s][7], R22 = pR[s][8];
        // Refill slot s with joint i+PF (issues ahead of this joint's FMAs).
        if (i + PF < 24) {
#pragma unroll
            for (int v = 0; v < 3; ++v) pJ[s][v] = Jb[3*(i+PF) + v];
#pragma unroll
            for (int v = 0; v < 9; ++v) pR[s][v] = Rb[9*(i+PF) + v];
        }

        jx[i] = jix; jy[i] = jiy; jz[i] = jiz;

        float b0, b1, b2, t;
        if (i == 0) {
            b0 = rb0; b1 = rb1; b2 = rb2; t = rt;
        } else {
            const int p = PARENTS[i];
            const float c0 = a0[p], c1 = a1[p], c2 = a2[p];
            const float rl0 = jix - jx[p], rl1 = jiy - jy[p], rl2 = jiz - jz[p];
            b0 = c0*R00 + c1*R10 + c2*R20;
            b1 = c0*R01 + c1*R11 + c2*R21;
            b2 = c0*R02 + c1*R12 + c2*R22;
            t  = c0*rl0 + c1*rl1 + c2*rl2 + tg[p];
        }
        a0[i] = b0; a1[i] = b1; a2[i] = b2; tg[i] = t;

        // rel row: [row | t - row.j_i]; lane 3 substitutes (0,0,0,1).
        const float tc = t - (b0*jix + b1*jiy + b2*jiz);
        f32x4 out;
        if (rowlane) { out.x = b0; out.y = b1; out.z = b2; out.w = tc; }
        else         { out.x = 0.f; out.y = 0.f; out.z = 0.f; out.w = 1.f; }
        // Quad writes 64 B contiguous; 16 full cache lines per instruction.
        __builtin_nontemporal_store(out, relG + 4*i + r);
    }

    // ---- Stage posed components (batched; tg[] is register-resident).
    if (rowlane) {
#pragma unroll
        for (int i = 0; i < 24; ++i) smem[bw*76 + 3*i + r] = tg[i];
    }

    wave_sync();   // order own-wave ds_writes before the transpose reads

    // posed flush: this wave's 16 bodies are contiguous -> 288 float4.
    const f32x4* s4 = reinterpret_cast<const f32x4*>(smem) + w * 304; // 16*19
    f32x4* pos4 = reinterpret_cast<f32x4*>(posed)
                + ((size_t)blockIdx.x * 64 + (w << 4)) * 18;
#pragma unroll
    for (int t5 = 0; t5 < 5; ++t5) {
        const int g = t5*64 + l;                // 0..319, need < 288
        if (g < 288) {
            const int bdy = g / 18;             // magic-mul division
            const int k   = g - bdy*18;
            const f32x4 v = s4[bdy*19 + k];
            __builtin_nontemporal_store(v, pos4 + g);
        }
    }
}

extern "C" void kernel_launch(void* const* d_in, const int* in_sizes, int n_in,
                              void* d_out, int out_size, void* d_ws, size_t ws_size,
                              hipStream_t stream) {
    const float* rot = (const float*)d_in[0];   // (B,24,3,3)
    const float* jts = (const float*)d_in[1];   // (B,24,3)
    const int B = in_sizes[1] / 72;             // 24*3 floats per body

    float* posed = (float*)d_out;                       // B*24*3
    float* rel   = posed + (size_t)B * 72;              // B*24*16

    const int block = 256;                      // 4 waves, 64 bodies/block
    const int grid  = B / 64;                   // 65536 -> 1024 blocks
    hipLaunchKernelGGL(fk_kernel, dim3(grid), dim3(block), 0, stream,
                       rot, jts, posed, rel, B);
}

// Round 4
// 189.881 us; speedup vs baseline: 1.1904x; 1.1127x over previous
//
#include <hip/hip_runtime.h>

// ForwardKinematics: B=65536 bodies, N=24 joints, compile-time parent tree.
//
// Round 7: LDS-staged inputs. Rounds 5/6 post-mortems (VGPR=36/64,
// VALUBusy ~5%, 1.8-2.2 TB/s) showed the chain's per-joint quad-uniform
// HBM loads are JIT-scheduled by the compiler regardless of source-level
// prefetch windows (regalloc sinks refills to their use), exposing full
// memory latency 24 times per wave, on top of poor per-instruction TA
// efficiency (16 scattered 36 B chunks per dwordx4).
//
// Fix: bulk-stage each block's inputs into LDS first.
//   - Copy is contiguous: 64 lanes x 16 B per instruction, all loads
//     independent and issued before any consumer (progressive vmcnt
//     pipelining, ~300 B/lane in flight) -- HBM-BW-bound, not latency.
//   - Chain then reads from LDS (~120 cy), where JIT scheduling is cheap.
//   - LDS body strides padded: rot 216->220 words, jts 72->76 words, so
//     quad-uniform chain reads alias worst-case 2-way (free). Padding is
//     implemented in the staging SOURCE map (pad slots load dup garbage);
//     the ds_write stream stays lane-linear b128, conflict-free.
//   - One wave per block (16 bodies): all sync is wave-synchronous
//     compiler fences; zero s_barrier, zero explicit vmcnt drains.
//     18944 B LDS -> 8 blocks/CU = 2 waves/SIMD.
//
// Carried: 4 lanes/body row-split (lanes 0-2 own row-chains, lane 3 the
// constant bottom row); rel direct-from-register full-line nontemporal
// stores; posed transposed through LDS (reusing the jts region) and
// flushed as full lines.

typedef float f32x4 __attribute__((ext_vector_type(4)));

constexpr int PARENTS[24] = {-1, 0, 0, 0, 1, 2, 3, 4, 5, 6, 7, 8,
                             9, 9, 9, 12, 13, 14, 16, 17, 18, 19, 20, 21};

constexpr int NB        = 16;        // bodies per block (one wave)
constexpr int ROTW      = 220;       // words/body in rot LDS (216 + 4 pad)
constexpr int JTW       = 76;        // words/body in jts LDS (72 + 4 pad)
constexpr int ROT_WORDS = NB * ROTW; // 3520 words = 880 f4 slots
constexpr int JT_WORDS  = NB * JTW;  // 1216 words = 304 f4 slots

// Wave-synchronous "barrier": one wave's DS ops execute in order in the DS
// pipe; cross-step LDS hazards inside a wave need only a compiler fence.
__device__ __forceinline__ void wave_sync() {
    asm volatile("" ::: "memory");
    __builtin_amdgcn_wave_barrier();
    asm volatile("" ::: "memory");
}

__global__ __launch_bounds__(64, 2)
void fk_kernel(const float* __restrict__ rot,   // (B,24,3,3)
               const float* __restrict__ jts,   // (B,24,3)
               float* __restrict__ posed,       // (B,24,3)
               float* __restrict__ rel,         // (B,24,4,4)
               int B)
{
    __shared__ float smem[ROT_WORDS + JT_WORDS];   // 4736 floats = 18944 B
    f32x4* sf4 = reinterpret_cast<f32x4*>(smem);

    const int l = threadIdx.x;                  // 0..63
    const int q = l >> 2;                       // body-in-block 0..15
    const int r = l & 3;                        // row lane (3 = bottom row)
    const int body0 = blockIdx.x * NB;
    const int body  = body0 + q;
    const bool rowlane = (r < 3);

    const float* Rw = rot + (size_t)body0 * 216;
    const float* Jw = jts + (size_t)body0 * 72;

    // ---- Stage: load everything to registers first (all independent ->
    // issued back-to-back), then write to LDS (each write waits only on
    // its own load: progressive vmcnt pipelining).
    f32x4 stR[14], stJ[5];
#pragma unroll
    for (int s = 0; s < 14; ++s) {
        const int g = s * 64 + l;               // f4 slot in rot region
        if (g < 880) {
            const int dw = g * 4;               // dest word
            const int b  = dw / ROTW;           // body (magic-mul)
            const int k0 = dw - b * ROTW;       // word within padded body
            const int k  = (k0 <= 212) ? k0 : 212;   // pad quad -> dup tail
            stR[s] = *reinterpret_cast<const f32x4*>(Rw + b * 216 + k);
        }
    }
#pragma unroll
    for (int s = 0; s < 5; ++s) {
        const int g = s * 64 + l;               // f4 slot in jts region
        if (g < 304) {
            const int dw = g * 4;
            const int b  = dw / JTW;
            const int k0 = dw - b * JTW;
            const int k  = (k0 <= 68) ? k0 : 68;
            stJ[s] = *reinterpret_cast<const f32x4*>(Jw + b * 72 + k);
        }
    }
#pragma unroll
    for (int s = 0; s < 14; ++s) {
        const int g = s * 64 + l;
        if (g < 880) sf4[g] = stR[s];           // lane-linear b128, no conflicts
    }
#pragma unroll
    for (int s = 0; s < 5; ++s) {
        const int g = s * 64 + l;
        if (g < 304) sf4[880 + g] = stJ[s];
    }

    wave_sync();   // order staging ds_writes before chain ds_reads

    // ---- Chain, reading from LDS (quad-uniform addrs: 2-way alias, free).
    const float* rS = smem + ROTW * q;              // this quad's rot
    const float* jS = smem + ROT_WORDS + JTW * q;   // this quad's jts

    f32x4* relG = reinterpret_cast<f32x4*>(rel) + (size_t)body * 96;

    // Constant-indexed after full unroll -> registers with true liveness.
    float jx[24], jy[24], jz[24];
    float a0[24], a1[24], a2[24];   // this lane's row of the global rotation
    float tg[24];                   // this lane's component of global translation

#pragma unroll
    for (int i = 0; i < 24; ++i) {
        const float jix = jS[3*i+0], jiy = jS[3*i+1], jiz = jS[3*i+2];
        jx[i] = jix; jy[i] = jiy; jz[i] = jiz;

        float b0, b1, b2, t;
        if (i == 0) {
            // Own row of R_0 (per-lane addr; lane 3 reads in-bounds garbage,
            // masked at the store below).
            b0 = rS[3*r+0]; b1 = rS[3*r+1]; b2 = rS[3*r+2];
            t  = jS[r];
        } else {
            const float R00 = rS[9*i+0], R01 = rS[9*i+1], R02 = rS[9*i+2];
            const float R10 = rS[9*i+3], R11 = rS[9*i+4], R12 = rS[9*i+5];
            const float R20 = rS[9*i+6], R21 = rS[9*i+7], R22 = rS[9*i+8];
            const int p = PARENTS[i];
            const float c0 = a0[p], c1 = a1[p], c2 = a2[p];
            const float rl0 = jix - jx[p], rl1 = jiy - jy[p], rl2 = jiz - jz[p];
            b0 = c0*R00 + c1*R10 + c2*R20;
            b1 = c0*R01 + c1*R11 + c2*R21;
            b2 = c0*R02 + c1*R12 + c2*R22;
            t  = c0*rl0 + c1*rl1 + c2*rl2 + tg[p];
        }
        a0[i] = b0; a1[i] = b1; a2[i] = b2; tg[i] = t;

        // rel row: [row | t - row.j_i]; lane 3 substitutes (0,0,0,1).
        const float tc = t - (b0*jix + b1*jiy + b2*jiz);
        f32x4 out;
        if (rowlane) { out.x = b0; out.y = b1; out.z = b2; out.w = tc; }
        else         { out.x = 0.f; out.y = 0.f; out.z = 0.f; out.w = 1.f; }
        // Quad writes 64 B contiguous; 16 full cache lines per instruction.
        __builtin_nontemporal_store(out, relG + 4*i + r);
    }

    // ---- posed: reuse the jts LDS region (its reads are done).
    wave_sync();   // order chain ds_reads before the overwrite
    if (rowlane) {
#pragma unroll
        for (int i = 0; i < 24; ++i)
            smem[ROT_WORDS + JTW * q + 3*i + r] = tg[i];   // 2-way alias, free
    }
    wave_sync();   // order posed ds_writes before the transpose reads

    // Flush: block's 16 bodies are contiguous -> 288 float4.
    const f32x4* s4 = reinterpret_cast<const f32x4*>(smem + ROT_WORDS); // stride 19 f4
    f32x4* pos4 = reinterpret_cast<f32x4*>(posed) + (size_t)body0 * 18;
#pragma unroll
    for (int s = 0; s < 5; ++s) {
        const int g = s * 64 + l;               // 0..319, need < 288
        if (g < 288) {
            const int bdy = g / 18;             // magic-mul division
            const int k   = g - bdy * 18;
            const f32x4 v = s4[bdy * 19 + k];
            __builtin_nontemporal_store(v, pos4 + g);
        }
    }
}

extern "C" void kernel_launch(void* const* d_in, const int* in_sizes, int n_in,
                              void* d_out, int out_size, void* d_ws, size_t ws_size,
                              hipStream_t stream) {
    const float* rot = (const float*)d_in[0];   // (B,24,3,3)
    const float* jts = (const float*)d_in[1];   // (B,24,3)
    const int B = in_sizes[1] / 72;             // 24*3 floats per body

    float* posed = (float*)d_out;                       // B*24*3
    float* rel   = posed + (size_t)B * 72;              // B*24*16

    const int block = 64;                       // one wave, 16 bodies
    const int grid  = B / NB;                   // 65536/16 = 4096 blocks
    hipLaunchKernelGGL(fk_kernel, dim3(grid), dim3(block), 0, stream,
                       rot, jts, posed, rel, B);
}

// Round 5
// 181.467 us; speedup vs baseline: 1.2456x; 1.0464x over previous
//
#include <hip/hip_runtime.h>

// ForwardKinematics: B=65536 bodies, N=24 joints, compile-time parent tree.
//
// Round 8: register-resident inputs shared across the quad via DPP
// quad_perm broadcasts. Session history: every kernel that paid per-joint
// memory latency in the chain lost (r5/r6: HBM JIT loads, 87-100us;
// r7: LDS JIT reads + 2 waves/SIMD, 70.8us); the register-pure chain
// (r3) was fastest but needed 500 VGPR -> 1 wave/SIMD.
//
// This version gets BOTH: 4 lanes/body, lane r holds input f4-slots
// s==r (mod 4) -> 72 floats/lane (76 VGPR). Each R/j element's
// (owner-lane, register, element) coordinate is COMPILE-TIME (template-
// recursed chain), so v_mov_b32_dpp quad_perm broadcasts it to the quad:
// pure VALU, no memory pipe, no latency. All 19 input loads issue in one
// burst (304 B/lane MLP, the round-3 pattern that worked), pinned above
// the chain by sched_barrier(0) so the compiler cannot re-sink them to
// their uses (the round-6 failure).
//
// LDS now only stages the posed transpose (4864 B) -> occupancy is
// VGPR-bound; launch_bounds(64,4) targets <=128 VGPR = 4 waves/SIMD =
// the entire 4096-wave grid resident in one generation.
//
// rel stores: DROPPED nontemporal. Quad writes 64 B; HBM/L2 write granule
// is 128 B, and joint i / i+1 halves of a line are stored ~40 inst apart.
// No-allocate streaming stores can't merge them -> partial-line RMW
// (round-7 WRITE_SIZE 145 MB vs 119.5 ideal). Plain stores let L2
// allocate and merge before eviction.

typedef float f32x4 __attribute__((ext_vector_type(4)));
typedef int   i32x4 __attribute__((ext_vector_type(4)));

constexpr int PARENTS[24] = {-1, 0, 0, 0, 1, 2, 3, 4, 5, 6, 7, 8,
                             9, 9, 9, 12, 13, 14, 16, 17, 18, 19, 20, 21};

// Wave-synchronous "barrier": one wave's DS ops execute in order in the DS
// pipe; cross-step LDS hazards inside a wave need only a compiler fence.
__device__ __forceinline__ void wave_sync() {
    asm volatile("" ::: "memory");
    __builtin_amdgcn_wave_barrier();
    asm volatile("" ::: "memory");
}

// Broadcast lane O's (within each quad) value of x to the whole quad.
// quad_perm ctrl = O in all four 2-bit selects = O * 0x55. Pure VALU.
template<int O>
__device__ __forceinline__ float qbf(int x) {
    return __builtin_bit_cast(float,
        __builtin_amdgcn_update_dpp(0, x, (O) * 0x55, 0xF, 0xF, true));
}

// Fetch rot float (9*I+m) / jts float (3*J+m) of this quad's body from the
// distributed register file. slot s = f>>2; owner = s&3; local reg = s>>2;
// elem = f&3 -- all integer constant expressions (I, m are template/literal).
#define RBC(I, m) qbf<(((9*(I)+(m)) >> 2) & 3)>( rin[((9*(I)+(m)) >> 2) >> 2][(9*(I)+(m)) & 3] )
#define JBC(J, m) qbf<(((3*(J)+(m)) >> 2) & 3)>( jin[((3*(J)+(m)) >> 2) >> 2][(3*(J)+(m)) & 3] )

template<int I>
__device__ __forceinline__ void chain_step(
    const i32x4 (&rin)[14], const i32x4 (&jin)[5],
    float (&a0)[24], float (&a1)[24], float (&a2)[24], float (&tg)[24],
    int r, bool rowlane, f32x4* relG, float* sp)
{
    const float jx = JBC(I, 0), jy = JBC(I, 1), jz = JBC(I, 2);
    float b0, b1, b2, t;
    if constexpr (I == 0) {
        // Root: broadcast all of R_0, lane r selects its row; t = j0[r].
        // Lane 3 takes the r==2 path -> garbage, masked at the store.
        const float F0 = RBC(0,0), F1 = RBC(0,1), F2 = RBC(0,2),
                    F3 = RBC(0,3), F4 = RBC(0,4), F5 = RBC(0,5),
                    F6 = RBC(0,6), F7 = RBC(0,7), F8 = RBC(0,8);
        b0 = r == 0 ? F0 : (r == 1 ? F3 : F6);
        b1 = r == 0 ? F1 : (r == 1 ? F4 : F7);
        b2 = r == 0 ? F2 : (r == 1 ? F5 : F8);
        t  = r == 0 ? jx : (r == 1 ? jy : jz);
    } else {
        constexpr int P = PARENTS[I];
        const float R00 = RBC(I,0), R01 = RBC(I,1), R02 = RBC(I,2),
                    R10 = RBC(I,3), R11 = RBC(I,4), R12 = RBC(I,5),
                    R20 = RBC(I,6), R21 = RBC(I,7), R22 = RBC(I,8);
        // Parent joint re-broadcast from input regs (cheaper than keeping
        // per-lane j copies live: 3 DPP movs vs 3 VGPRs x window).
        const float px = JBC(P, 0), py = JBC(P, 1), pz = JBC(P, 2);
        const float c0 = a0[P], c1 = a1[P], c2 = a2[P];
        b0 = c0*R00 + c1*R10 + c2*R20;
        b1 = c0*R01 + c1*R11 + c2*R21;
        b2 = c0*R02 + c1*R12 + c2*R22;
        t  = c0*(jx - px) + c1*(jy - py) + c2*(jz - pz) + tg[P];
    }
    a0[I] = b0; a1[I] = b1; a2[I] = b2; tg[I] = t;

    // rel row: [row | t - row.j_i]; lane 3 substitutes (0,0,0,1).
    const float tc = t - (b0*jx + b1*jy + b2*jz);
    f32x4 out;
    out.x = rowlane ? b0 : 0.f;
    out.y = rowlane ? b1 : 0.f;
    out.z = rowlane ? b2 : 0.f;
    out.w = rowlane ? tc : 1.f;
    relG[4*I + r] = out;           // quad: 64 B contiguous; plain store -> L2 merges lines

    // posed component staged per joint (keeps tg liveness short). Lane 3
    // dumps into the 4-float pad -- branchless, no exec-mask churn.
    const int ofs = rowlane ? (3*I + r) : (72 + (I & 3));
    sp[ofs] = t;
}

template<int I>
__device__ __forceinline__ void chain_all(
    const i32x4 (&rin)[14], const i32x4 (&jin)[5],
    float (&a0)[24], float (&a1)[24], float (&a2)[24], float (&tg)[24],
    int r, bool rowlane, f32x4* relG, float* sp)
{
    chain_step<I>(rin, jin, a0, a1, a2, tg, r, rowlane, relG, sp);
    if constexpr (I + 1 < 24)
        chain_all<I + 1>(rin, jin, a0, a1, a2, tg, r, rowlane, relG, sp);
}

__global__ __launch_bounds__(64, 4)
void fk_kernel(const float* __restrict__ rot,   // (B,24,3,3)
               const float* __restrict__ jts,   // (B,24,3)
               float* __restrict__ posed,       // (B,24,3)
               float* __restrict__ rel,         // (B,24,4,4)
               int B)
{
    __shared__ float smem[16 * 76];             // 4864 B: posed transpose only

    const int l = threadIdx.x;                  // 0..63
    const int q = l >> 2;                       // body-in-block 0..15
    const int r = l & 3;                        // row lane (3 = bottom row)
    const bool rowlane = (r < 3);
    const int body = blockIdx.x * 16 + q;

    // ---- Bulk input burst: lane r owns f4-slots s==r (mod 4) of its
    // body's 54 rot + 18 jts slots. 19 independent loads, 304 B/lane in
    // flight. Tail slots clamp (duplicate loads, never DPP-sourced from
    // the clamped lanes). Per instruction: 16 quads x 64 B chunks.
    const i32x4* rot4 = reinterpret_cast<const i32x4*>(rot) + (size_t)body * 54;
    const i32x4* jt4  = reinterpret_cast<const i32x4*>(jts) + (size_t)body * 18;
    i32x4 rin[14], jin[5];
#pragma unroll
    for (int n = 0; n < 14; ++n) { int s = 4*n + r; s = s > 53 ? 53 : s; rin[n] = rot4[s]; }
#pragma unroll
    for (int n = 0; n < 5;  ++n) { int s = 4*n + r; s = s > 17 ? 17 : s; jin[n] = jt4[s]; }
    // Pin the burst above the chain: round 6 showed the scheduler sinks
    // loads to their first use (JIT, MLP=1) if allowed.
    __builtin_amdgcn_sched_barrier(0);

    float a0[24], a1[24], a2[24], tg[24];       // liveness-pruned by unroll
    f32x4* relG = reinterpret_cast<f32x4*>(rel) + (size_t)body * 96;
    chain_all<0>(rin, jin, a0, a1, a2, tg, r, rowlane, relG, smem + q * 76);

    wave_sync();   // order per-joint posed ds_writes before transpose reads

    // posed flush: block's 16 bodies are contiguous -> 288 float4 at
    // blockIdx*4608 B (128 B aligned, full lines per instruction).
    const f32x4* s4 = reinterpret_cast<const f32x4*>(smem);   // stride 19 f4/body
    f32x4* pos4 = reinterpret_cast<f32x4*>(posed) + (size_t)blockIdx.x * 288;
#pragma unroll
    for (int u = 0; u < 5; ++u) {
        const int g = u * 64 + l;               // 0..319, need < 288
        if (g < 288) {
            const int bdy = g / 18;             // magic-mul division
            const int k   = g - bdy * 18;
            pos4[g] = s4[bdy * 19 + k];
        }
    }
}

extern "C" void kernel_launch(void* const* d_in, const int* in_sizes, int n_in,
                              void* d_out, int out_size, void* d_ws, size_t ws_size,
                              hipStream_t stream) {
    const float* rot = (const float*)d_in[0];   // (B,24,3,3)
    const float* jts = (const float*)d_in[1];   // (B,24,3)
    const int B = in_sizes[1] / 72;             // 24*3 floats per body

    float* posed = (float*)d_out;                       // B*24*3
    float* rel   = posed + (size_t)B * 72;              // B*24*16

    const int block = 64;                       // one wave, 16 bodies (4 lanes/body)
    const int grid  = B / 16;                   // 65536/16 = 4096 blocks
    hipLaunchKernelGGL(fk_kernel, dim3(grid), dim3(block), 0, stream,
                       rot, jts, posed, rel, B);
}

// Round 6
// 176.906 us; speedup vs baseline: 1.2777x; 1.0258x over previous
//
#include <hip/hip_runtime.h>

// ForwardKinematics: B=65536 bodies, N=24 joints, compile-time parent tree.
//
// Round 9 = round 8 (DPP register chain, 4 waves/SIMD) + round 3's
// full-line LDS-staged rel flush.
//
// Round-8 post-mortem: fk ~60us moving 195 MB = 3.25 TB/s -- almost
// exactly HALF the 6.3 TB/s copy ceiling. The quad rel stores are 16
// scattered 64 B chunks per instruction (half a 128 B line each, stride
// 1536 B); writes aren't L1-merged, so the 120 MB write stream (62% of
// traffic) runs the L2/TA path at half-line throughput. The poison fills
// (6.8 TB/s) and m13 copy (6.29) both write full lines per segment.
//
// Fix: stage each 4-joint chunk of rel rows in LDS (stride 17 f4/body --
// round 3 measured this exact pattern at 0 bank conflicts) and flush with
// full-line stores: each flush instruction = 4 bodies x 256 B contiguous
// (8 full 128 B lines), vs 16 half-lines before.
//
// Carried from round 8:
//  - 4 lanes/body; lane r holds input f4-slots s==r (mod 4) -> 76 VGPR of
//    inputs; every R/j element is DPP quad_perm-broadcast at a compile-time
//    (owner, reg, elem) coordinate; chain is pure VALU, zero loads.
//  - 19-instruction input burst pinned above the chain by sched_barrier(0)
//    (round 6 showed the scheduler otherwise sinks loads to first use).
//  - one wave/block; all ordering via wave-synchronous compiler fences
//    (in-order DS pipe per wave) -- no s_barrier, no vmcnt drains; global
//    stores stay in flight across chunks.
//  - posed staged at stride 19 f4/body, flushed as 5 full-line instructions.
// LDS = 272 f4 (rel chunk) + 16*76 words (posed) = 9216 B -> 16 blocks/CU
// keeps 4 waves/SIMD.

typedef float f32x4 __attribute__((ext_vector_type(4)));
typedef int   i32x4 __attribute__((ext_vector_type(4)));

constexpr int PARENTS[24] = {-1, 0, 0, 0, 1, 2, 3, 4, 5, 6, 7, 8,
                             9, 9, 9, 12, 13, 14, 16, 17, 18, 19, 20, 21};

constexpr int RELW       = 17;            // f4 per body, rel chunk region
constexpr int REL_WORDS  = 16 * RELW * 4; // 1088 words
constexpr int POSW       = 76;            // words per body, posed region

// Wave-synchronous "barrier": one wave's DS ops execute in order in the DS
// pipe; cross-step LDS hazards inside a wave need only a compiler fence.
__device__ __forceinline__ void wave_sync() {
    asm volatile("" ::: "memory");
    __builtin_amdgcn_wave_barrier();
    asm volatile("" ::: "memory");
}

// Broadcast lane O's (within each quad) value of x to the whole quad.
// quad_perm ctrl = O in all four 2-bit selects = O * 0x55. Pure VALU.
template<int O>
__device__ __forceinline__ float qbf(int x) {
    return __builtin_bit_cast(float,
        __builtin_amdgcn_update_dpp(0, x, (O) * 0x55, 0xF, 0xF, true));
}

// Fetch rot float (9*I+m) / jts float (3*J+m) of this quad's body from the
// distributed register file. slot s = f>>2; owner = s&3; local reg = s>>2;
// elem = f&3 -- all integer constant expressions.
#define RBC(I, m) qbf<(((9*(I)+(m)) >> 2) & 3)>( rin[((9*(I)+(m)) >> 2) >> 2][(9*(I)+(m)) & 3] )
#define JBC(J, m) qbf<(((3*(J)+(m)) >> 2) & 3)>( jin[((3*(J)+(m)) >> 2) >> 2][(3*(J)+(m)) & 3] )

template<int I>
__device__ __forceinline__ void chain_step(
    const i32x4 (&rin)[14], const i32x4 (&jin)[5],
    float (&a0)[24], float (&a1)[24], float (&a2)[24], float (&tg)[24],
    int l, int q, int r, bool rowlane,
    f32x4* srel, float* sp, f32x4* relB)
{
    const float jx = JBC(I, 0), jy = JBC(I, 1), jz = JBC(I, 2);
    float b0, b1, b2, t;
    if constexpr (I == 0) {
        // Root: broadcast all of R_0, lane r selects its row; t = j0[r].
        // Lane 3 takes the r==2 path -> garbage, masked at the stage below.
        const float F0 = RBC(0,0), F1 = RBC(0,1), F2 = RBC(0,2),
                    F3 = RBC(0,3), F4 = RBC(0,4), F5 = RBC(0,5),
                    F6 = RBC(0,6), F7 = RBC(0,7), F8 = RBC(0,8);
        b0 = r == 0 ? F0 : (r == 1 ? F3 : F6);
        b1 = r == 0 ? F1 : (r == 1 ? F4 : F7);
        b2 = r == 0 ? F2 : (r == 1 ? F5 : F8);
        t  = r == 0 ? jx : (r == 1 ? jy : jz);
    } else {
        constexpr int P = PARENTS[I];
        const float R00 = RBC(I,0), R01 = RBC(I,1), R02 = RBC(I,2),
                    R10 = RBC(I,3), R11 = RBC(I,4), R12 = RBC(I,5),
                    R20 = RBC(I,6), R21 = RBC(I,7), R22 = RBC(I,8);
        const float px = JBC(P, 0), py = JBC(P, 1), pz = JBC(P, 2);
        const float c0 = a0[P], c1 = a1[P], c2 = a2[P];
        b0 = c0*R00 + c1*R10 + c2*R20;
        b1 = c0*R01 + c1*R11 + c2*R21;
        b2 = c0*R02 + c1*R12 + c2*R22;
        t  = c0*(jx - px) + c1*(jy - py) + c2*(jz - pz) + tg[P];
    }
    a0[I] = b0; a1[I] = b1; a2[I] = b2; tg[I] = t;

    // Stage rel row in LDS: [row | t - row.j_i]; lane 3 stages (0,0,0,1).
    const float tc = t - (b0*jx + b1*jy + b2*jz);
    f32x4 out;
    out.x = rowlane ? b0 : 0.f;
    out.y = rowlane ? b1 : 0.f;
    out.z = rowlane ? b2 : 0.f;
    out.w = rowlane ? tc : 1.f;
    srel[q * RELW + (I & 3) * 4 + r] = out;     // round-3 stride: conflict-free

    // posed component; lane 3 dumps into the 4-float pad (branchless).
    const int ofs = rowlane ? (3*I + r) : (72 + (I & 3));
    sp[ofs] = t;

    // Every 4th joint: flush the chunk with FULL-LINE stores.
    if constexpr ((I & 3) == 3) {
        wave_sync();                            // ds_writes before flush reads
        constexpr int c = I >> 2;               // chunk 0..5
#pragma unroll
        for (int u = 0; u < 4; ++u) {
            const int bdy = u * 4 + (l >> 4);   // 0..15
            const int f4i = l & 15;             // 0..15
            // Per instruction: 4 segments x 256 B contiguous = 8 full lines.
            relB[(size_t)bdy * 96 + c * 16 + f4i] = srel[bdy * RELW + f4i];
        }
        wave_sync();                            // flush reads before next writes
    }
}

template<int I>
__device__ __forceinline__ void chain_all(
    const i32x4 (&rin)[14], const i32x4 (&jin)[5],
    float (&a0)[24], float (&a1)[24], float (&a2)[24], float (&tg)[24],
    int l, int q, int r, bool rowlane,
    f32x4* srel, float* sp, f32x4* relB)
{
    chain_step<I>(rin, jin, a0, a1, a2, tg, l, q, r, rowlane, srel, sp, relB);
    if constexpr (I + 1 < 24)
        chain_all<I + 1>(rin, jin, a0, a1, a2, tg, l, q, r, rowlane, srel, sp, relB);
}

__global__ __launch_bounds__(64, 4)
void fk_kernel(const float* __restrict__ rot,   // (B,24,3,3)
               const float* __restrict__ jts,   // (B,24,3)
               float* __restrict__ posed,       // (B,24,3)
               float* __restrict__ rel,         // (B,24,4,4)
               int B)
{
    __shared__ float smem[REL_WORDS + 16 * POSW];   // 2304 words = 9216 B

    const int l = threadIdx.x;                  // 0..63
    const int q = l >> 2;                       // body-in-block 0..15
    const int r = l & 3;                        // row lane (3 = bottom row)
    const bool rowlane = (r < 3);
    const int body0 = blockIdx.x * 16;
    const int body  = body0 + q;

    // ---- Bulk input burst: lane r owns f4-slots s==r (mod 4) of its
    // body's 54 rot + 18 jts slots. 19 independent loads, 304 B/lane in
    // flight. Tail slots clamp (dup loads, never DPP-sourced).
    const i32x4* rot4 = reinterpret_cast<const i32x4*>(rot) + (size_t)body * 54;
    const i32x4* jt4  = reinterpret_cast<const i32x4*>(jts) + (size_t)body * 18;
    i32x4 rin[14], jin[5];
#pragma unroll
    for (int n = 0; n < 14; ++n) { int s = 4*n + r; s = s > 53 ? 53 : s; rin[n] = rot4[s]; }
#pragma unroll
    for (int n = 0; n < 5;  ++n) { int s = 4*n + r; s = s > 17 ? 17 : s; jin[n] = jt4[s]; }
    // Pin the burst above the chain (round 6: scheduler otherwise sinks
    // loads to first use, MLP=1).
    __builtin_amdgcn_sched_barrier(0);

    float a0[24], a1[24], a2[24], tg[24];       // liveness-pruned by unroll
    f32x4* srel = reinterpret_cast<f32x4*>(smem);
    float* sp   = smem + REL_WORDS + q * POSW;
    f32x4* relB = reinterpret_cast<f32x4*>(rel) + (size_t)body0 * 96;

    chain_all<0>(rin, jin, a0, a1, a2, tg, l, q, r, rowlane, srel, sp, relB);

    wave_sync();   // order posed ds_writes before transpose reads

    // posed flush: block's 16 bodies contiguous -> 288 float4 at
    // blockIdx*4608 B; 5 instructions x 1 KB contiguous (full lines).
    const f32x4* s4 = reinterpret_cast<const f32x4*>(smem + REL_WORDS); // stride 19 f4
    f32x4* pos4 = reinterpret_cast<f32x4*>(posed) + (size_t)blockIdx.x * 288;
#pragma unroll
    for (int u = 0; u < 5; ++u) {
        const int g = u * 64 + l;               // 0..319, need < 288
        if (g < 288) {
            const int bdy = g / 18;             // magic-mul division
            const int k   = g - bdy * 18;
            pos4[g] = s4[bdy * 19 + k];
        }
    }
}

extern "C" void kernel_launch(void* const* d_in, const int* in_sizes, int n_in,
                              void* d_out, int out_size, void* d_ws, size_t ws_size,
                              hipStream_t stream) {
    const float* rot = (const float*)d_in[0];   // (B,24,3,3)
    const float* jts = (const float*)d_in[1];   // (B,24,3)
    const int B = in_sizes[1] / 72;             // 24*3 floats per body

    float* posed = (float*)d_out;                       // B*24*3
    float* rel   = posed + (size_t)B * 72;              // B*24*16

    const int block = 64;                       // one wave, 16 bodies (4 lanes/body)
    const int grid  = B / 16;                   // 65536/16 = 4096 blocks
    hipLaunchKernelGGL(fk_kernel, dim3(grid), dim3(block), 0, stream,
                       rot, jts, posed, rel, B);
}